// Round 4
// baseline (382.259 us; speedup 1.0000x reference)
//
#include <hip/hip_runtime.h>

typedef __bf16 bf16x8 __attribute__((ext_vector_type(8)));
typedef float f32x4 __attribute__((ext_vector_type(4)));
typedef float f32x2 __attribute__((ext_vector_type(2)));

#define T_SEQ 30
#define NIN 26
#define XPITCH 780
#define LOG2E 1.44269504088896340736f

// sigmoid with argument pre-scaled by log2(e): sigma(a) where s = a*log2e
__device__ __forceinline__ float sig2(float s) {
    return __builtin_amdgcn_rcpf(1.f + __builtin_amdgcn_exp2f(-s));
}

// load one (row,t) chunk: 26 floats as 13 x f32x2 (8B-aligned)
#define LOADC(BUF, c, half) do {                                              \
    const int rr_ = (c) / 15, tt_ = (c) % 15 + (half) * 15;                   \
    const float* sp_ = x + (size_t)(b0 + rr_) * XPITCH + tt_ * NIN;           \
    _Pragma("unroll") for (int q_ = 0; q_ < 13; ++q_)                         \
        BUF[q_] = *(const f32x2*)(sp_ + 2 * q_);                              \
} while (0)

// convert + scatter one chunk into fragment-ready LDS (3 x b128 + tail b32)
#define WRITEC(BUF, c, half) do {                                             \
    const int rr_ = (c) / 15, tt_ = (c) % 15 + (half) * 15;                   \
    const int id_ = rr_ * 30 + tt_;                                           \
    const int ix_ = (id_ ^ ((rr_ >> 2) & 3)) << 3;                            \
    _Pragma("unroll") for (int kk_ = 0; kk_ < 3; ++kk_) {                     \
        bf16x8 wv_;                                                           \
        _Pragma("unroll") for (int q_ = 0; q_ < 4; ++q_) {                    \
            wv_[2 * q_]     = (__bf16)BUF[kk_ * 4 + q_].x;                    \
            wv_[2 * q_ + 1] = (__bf16)BUF[kk_ * 4 + q_].y;                    \
        }                                                                     \
        *(bf16x8*)&xmain[kk_ * 7680 + ix_] = wv_;                             \
    }                                                                         \
    xtail[id_ * 2]     = (__bf16)BUF[12].x;                                   \
    xtail[id_ * 2 + 1] = (__bf16)BUF[12].y;                                   \
} while (0)

__global__ __launch_bounds__(128, 2) void gru_kernel(
    const float* __restrict__ x, const float* __restrict__ W_ih,
    const float* __restrict__ W_hh, const float* __restrict__ b_ih,
    const float* __restrict__ b_hh, const float* __restrict__ fc1_w,
    const float* __restrict__ fc1_b, const float* __restrict__ fc2_w,
    const float* __restrict__ fc2_b, float* __restrict__ out)
{
    // x panel, fragment-ready: xmain[kg][ (row*30+t)^swz ][8] bf16 (kg=0..2), 16B chunks
    __shared__ __attribute__((aligned(16))) __bf16 xmain[23040];  // 46080 B
    __shared__ __attribute__((aligned(8)))  __bf16 xtail[1920];   // k=24,25  (3840 B)
    __shared__ __attribute__((aligned(16))) __bf16 hbuf[1024];    // 2 waves x [16][32]
    __shared__ float wbuf[236];  // fc1_w[0..191] fc1_b[192..199] fc2_w[200..231] fc2_b[232..235]

    const int tid = threadIdx.x;
    const int lane = tid & 63;
    const int wid = tid >> 6;          // 0..1
    const int m = lane & 15;           // A row / C col within tile
    const int kg = lane >> 4;          // k-chunk group
    const int w16 = wid << 4;
    const int b0 = blockIdx.x << 5;    // 32 batch rows per block

    // ---- stage fc weights + zero h ----
    for (int i = tid; i < 236; i += 128) {
        float v;
        if (i < 192) v = fc1_w[i];
        else if (i < 200) v = fc1_b[i - 192];
        else if (i < 232) v = fc2_w[i - 200];
        else v = fc2_b[i - 232];
        wbuf[i] = v;
    }
    for (int i = tid; i < 1024; i += 128) hbuf[i] = (__bf16)0.f;

    // ---- B fragments + biases from global (L2-hot), pre-scaled by log2e ----
    // padded N = 96: gate g' at cols 32g'..32g'+23 ; tile Tn = cols 16Tn..16Tn+15
    bf16x8 bIh[6], bHh[6];
    float bx[6], bh[6];
    #pragma unroll
    for (int Tn = 0; Tn < 6; ++Tn) {
        const float sc = (Tn < 4) ? LOG2E : (2.f * LOG2E);  // r,z: log2e ; n: 2log2e
        const int np = Tn * 16 + m;
        const int gp = np >> 5;
        const int jh = np & 31;
        const bool vc = jh < 24;
        const int g = gp * 24 + jh;
        #pragma unroll
        for (int e = 0; e < 8; ++e) {
            const int k = kg * 8 + e;
            bIh[Tn][e] = (__bf16)((vc && k < 26) ? W_ih[g * 26 + k] * sc : 0.f);
            bHh[Tn][e] = (__bf16)((vc && k < 24) ? W_hh[g * 24 + k] * sc : 0.f);
        }
        bx[Tn] = vc ? b_ih[g] * sc : 0.f;
        bh[Tn] = vc ? b_hh[g] * sc : 0.f;
    }
    const float brz0 = bx[0] + bh[0], brz1 = bx[1] + bh[1];
    const float brz2 = bx[2] + bh[2], brz3 = bx[3] + bh[3];
    const float bnx0 = bx[4], bnh0 = bh[4], bnx1 = bx[5], bnh1 = bh[5];

    // ---- stage half-1 (t=0..14): 480 chunks, 2-deep pipelined ----
    {
        f32x2 bufA[13], bufB[13];
        LOADC(bufA, tid, 0);
        #pragma unroll
        for (int j = 0; j < 4; ++j) {
            if (j < 3) {
                const int cn = tid + (j + 1) * 128;
                if (cn < 480) LOADC(bufB, cn, 0);
            }
            const int cc = tid + j * 128;
            if (cc < 480) WRITEC(bufA, cc, 0);
            if (j < 3) {
                #pragma unroll
                for (int q = 0; q < 13; ++q) bufA[q] = bufB[q];
            }
        }
    }
    __syncthreads();

    const int rowg = w16 + m;          // 0..31
    const int sxr = (rowg >> 2) & 3;
    const int rbase = rowg * 30;
    const int ra  = m * 32 + ((kg ^ (m >> 2)) << 3);
    const int wr0 = (kg * 4) * 32 + ((((m >> 3) ^ kg) & 3) << 3) + (m & 7);  // cols 0..15
    const int wr1 = (kg * 4) * 32 + (((2 ^ kg) & 3) << 3) + m;               // cols 16..23 (m<8)
    __bf16* hw = &hbuf[wid * 512];

    f32x4 hc0 = {0.f, 0.f, 0.f, 0.f}, hc1 = {0.f, 0.f, 0.f, 0.f};
    const f32x4 z4 = {0.f, 0.f, 0.f, 0.f};
    f32x2 bufS[13];

    #pragma unroll 1
    for (int t = 0; t < T_SEQ; ++t) {
        // half-2 staging interleaved: loads at t=1,3,5,7 land; writes at t=2,4,6,8
        if (t >= 1 && t <= 8) {
            if (t & 1) {
                const int c = tid + (((t - 1) >> 1) << 7);
                if (c < 480) LOADC(bufS, c, 1);
            } else {
                const int c = tid + (((t - 2) >> 1) << 7);
                if (c < 480) WRITEC(bufS, c, 1);
            }
        }
        if (t == 9) __syncthreads();   // half-2 visible before t=15 reads

        bf16x8 ax;
        {
            const int id = rbase + t;
            if (kg < 3) {
                ax = *(const bf16x8*)&xmain[kg * 7680 + ((id ^ sxr) << 3)];
            } else {
                bf16x8 zz = {};
                zz[0] = xtail[id * 2];
                zz[1] = xtail[id * 2 + 1];
                ax = zz;
            }
        }
        const bf16x8 ah = *(const bf16x8*)&hw[ra];

        // ---- tp = 0 : tiles 0 (r), 2 (z), 4 (n) ----
        {
            f32x4 xr = __builtin_amdgcn_mfma_f32_16x16x32_bf16(ax, bIh[0], z4, 0, 0, 0);
            f32x4 hr = __builtin_amdgcn_mfma_f32_16x16x32_bf16(ah, bHh[0], z4, 0, 0, 0);
            f32x4 xz = __builtin_amdgcn_mfma_f32_16x16x32_bf16(ax, bIh[2], z4, 0, 0, 0);
            f32x4 hz = __builtin_amdgcn_mfma_f32_16x16x32_bf16(ah, bHh[2], z4, 0, 0, 0);
            f32x4 xn = __builtin_amdgcn_mfma_f32_16x16x32_bf16(ax, bIh[4], z4, 0, 0, 0);
            f32x4 hn = __builtin_amdgcn_mfma_f32_16x16x32_bf16(ah, bHh[4], z4, 0, 0, 0);
            #pragma unroll
            for (int r = 0; r < 4; ++r) {
                const float rg = sig2(xr[r] + hr[r] + brz0);
                const float zg = sig2(xz[r] + hz[r] + brz2);
                const float ag = xn[r] + bnx0 + rg * (hn[r] + bnh0);
                const float ng = 2.f * sig2(ag) - 1.f;   // tanh via pre-scaled 2log2e
                hc0[r] = ng + zg * (hc0[r] - ng);
            }
            #pragma unroll
            for (int r = 0; r < 4; ++r)
                hw[wr0 + r * 32] = (__bf16)hc0[r];
        }

        // ---- tp = 1 : tiles 1 (r), 3 (z), 5 (n) ----
        {
            f32x4 xr = __builtin_amdgcn_mfma_f32_16x16x32_bf16(ax, bIh[1], z4, 0, 0, 0);
            f32x4 hr = __builtin_amdgcn_mfma_f32_16x16x32_bf16(ah, bHh[1], z4, 0, 0, 0);
            f32x4 xz = __builtin_amdgcn_mfma_f32_16x16x32_bf16(ax, bIh[3], z4, 0, 0, 0);
            f32x4 hz = __builtin_amdgcn_mfma_f32_16x16x32_bf16(ah, bHh[3], z4, 0, 0, 0);
            f32x4 xn = __builtin_amdgcn_mfma_f32_16x16x32_bf16(ax, bIh[5], z4, 0, 0, 0);
            f32x4 hn = __builtin_amdgcn_mfma_f32_16x16x32_bf16(ah, bHh[5], z4, 0, 0, 0);
            #pragma unroll
            for (int r = 0; r < 4; ++r) {
                const float rg = sig2(xr[r] + hr[r] + brz1);
                const float zg = sig2(xz[r] + hz[r] + brz3);
                const float ag = xn[r] + bnx1 + rg * (hn[r] + bnh1);
                const float ng = 2.f * sig2(ag) - 1.f;
                hc1[r] = ng + zg * (hc1[r] - ng);
            }
            if (m < 8) {
                #pragma unroll
                for (int r = 0; r < 4; ++r)
                    hw[wr1 + r * 32] = (__bf16)hc1[r];
            }
        }
    }

    // ---- epilogue: fc1 -> relu -> fc2 -> softmax, one lane per batch row ----
    if (lane < 16) {
        const int row = lane;
        float hv[24];
        #pragma unroll
        for (int j = 0; j < 24; ++j)
            hv[j] = (float)hw[row * 32 + ((((j >> 3) ^ (row >> 2)) & 3) << 3) + (j & 7)];
        float lg[4] = {wbuf[232], wbuf[233], wbuf[234], wbuf[235]};
        #pragma unroll
        for (int o = 0; o < 8; ++o) {
            float s = wbuf[192 + o];
            #pragma unroll
            for (int j = 0; j < 24; ++j) s += wbuf[o * 24 + j] * hv[j];
            s = fmaxf(s, 0.f);
            #pragma unroll
            for (int c = 0; c < 4; ++c) lg[c] += wbuf[200 + c * 8 + o] * s;
        }
        const float mx = fmaxf(fmaxf(lg[0], lg[1]), fmaxf(lg[2], lg[3]));
        const float e0 = __expf(lg[0] - mx), e1 = __expf(lg[1] - mx);
        const float e2 = __expf(lg[2] - mx), e3 = __expf(lg[3] - mx);
        const float inv = __builtin_amdgcn_rcpf(e0 + e1 + e2 + e3);
        f32x4 pr = {e0 * inv, e1 * inv, e2 * inv, e3 * inv};
        *(f32x4*)&out[(size_t)(b0 + w16 + row) * 4] = pr;
    }
}

extern "C" void kernel_launch(void* const* d_in, const int* in_sizes, int n_in,
                              void* d_out, int out_size, void* d_ws, size_t ws_size,
                              hipStream_t stream) {
    const float* xx    = (const float*)d_in[0];
    const float* w_ih  = (const float*)d_in[1];
    const float* w_hh  = (const float*)d_in[2];
    const float* bih   = (const float*)d_in[3];
    const float* bhh   = (const float*)d_in[4];
    const float* f1w   = (const float*)d_in[5];
    const float* f1b   = (const float*)d_in[6];
    const float* f2w   = (const float*)d_in[7];
    const float* f2b   = (const float*)d_in[8];
    float* outp = (float*)d_out;

    dim3 grid(65536 / 32), block(128);
    gru_kernel<<<grid, block, 0, stream>>>(xx, w_ih, w_hh, bih, bhh, f1w, f1b, f2w, f2b, outp);
}

// Round 5
// 356.716 us; speedup vs baseline: 1.0716x; 1.0716x over previous
//
#include <hip/hip_runtime.h>

typedef __bf16 bf16x8 __attribute__((ext_vector_type(8)));
typedef float f32x4 __attribute__((ext_vector_type(4)));
typedef float f32x2 __attribute__((ext_vector_type(2)));

#define T_SEQ 30
#define NIN 26
#define XPITCH 780
#define LOG2E 1.44269504088896340736f

// x window geometry (bf16 elems): [buf2][tw4][kg4][row64][8], kg padded 512->520
#define KGS 520
#define TWS (4 * KGS)     // 2080
#define BUFS (4 * TWS)    // 8320

// sigmoid with argument pre-scaled by log2(e)
__device__ __forceinline__ float sig2(float s) {
    return __builtin_amdgcn_rcpf(1.f + __builtin_amdgcn_exp2f(-s));
}

// stage-write: convert sb[13] (26 floats) -> 4 x ds_write_b128 into buffer BSEL
#define WSTORE(BSEL) do {                                                     \
    const int base_ = (BSEL) * BUFS + twn * TWS + rr * 8;                     \
    _Pragma("unroll") for (int kk_ = 0; kk_ < 3; ++kk_) {                     \
        bf16x8 wv_;                                                           \
        _Pragma("unroll") for (int q_ = 0; q_ < 4; ++q_) {                    \
            wv_[2 * q_]     = (__bf16)sb[kk_ * 4 + q_].x;                     \
            wv_[2 * q_ + 1] = (__bf16)sb[kk_ * 4 + q_].y;                     \
        }                                                                     \
        *(bf16x8*)&xwin[base_ + kk_ * KGS] = wv_;                             \
    }                                                                         \
    bf16x8 tv_ = {};                                                          \
    tv_[0] = (__bf16)sb[12].x; tv_[1] = (__bf16)sb[12].y;                     \
    *(bf16x8*)&xwin[base_ + 3 * KGS] = tv_;                                   \
} while (0)

// one GRU timestep: x fragment from window slot TT of buffer BSEL
#define STEP(TT, BSEL) do {                                                   \
    const bf16x8 ax = *(const bf16x8*)&xwin[(BSEL) * BUFS + (TT) * TWS + xoff]; \
    const bf16x8 ah = *(const bf16x8*)&hw[ra];                                \
    {   /* tp0: tiles 0(r) 2(z) 4(n) */                                       \
        f32x4 xr = __builtin_amdgcn_mfma_f32_16x16x32_bf16(ax, bIh[0], z4, 0, 0, 0); \
        f32x4 hr = __builtin_amdgcn_mfma_f32_16x16x32_bf16(ah, bHh[0], z4, 0, 0, 0); \
        f32x4 xz = __builtin_amdgcn_mfma_f32_16x16x32_bf16(ax, bIh[2], z4, 0, 0, 0); \
        f32x4 hz = __builtin_amdgcn_mfma_f32_16x16x32_bf16(ah, bHh[2], z4, 0, 0, 0); \
        f32x4 xn = __builtin_amdgcn_mfma_f32_16x16x32_bf16(ax, bIh[4], z4, 0, 0, 0); \
        f32x4 hn = __builtin_amdgcn_mfma_f32_16x16x32_bf16(ah, bHh[4], z4, 0, 0, 0); \
        _Pragma("unroll") for (int r = 0; r < 4; ++r) {                       \
            const float rg = sig2(xr[r] + hr[r] + brz0);                      \
            const float zg = sig2(xz[r] + hz[r] + brz2);                      \
            const float ag = xn[r] + bnx0 + rg * (hn[r] + bnh0);              \
            const float ng = 2.f * sig2(ag) - 1.f;                            \
            hc0[r] = ng + zg * (hc0[r] - ng);                                 \
        }                                                                     \
        _Pragma("unroll") for (int r = 0; r < 4; ++r)                         \
            hw[wr0 + r * 32] = (__bf16)hc0[r];                                \
    }                                                                         \
    {   /* tp1: tiles 1(r) 3(z) 5(n) */                                       \
        f32x4 xr = __builtin_amdgcn_mfma_f32_16x16x32_bf16(ax, bIh[1], z4, 0, 0, 0); \
        f32x4 hr = __builtin_amdgcn_mfma_f32_16x16x32_bf16(ah, bHh[1], z4, 0, 0, 0); \
        f32x4 xz = __builtin_amdgcn_mfma_f32_16x16x32_bf16(ax, bIh[3], z4, 0, 0, 0); \
        f32x4 hz = __builtin_amdgcn_mfma_f32_16x16x32_bf16(ah, bHh[3], z4, 0, 0, 0); \
        f32x4 xn = __builtin_amdgcn_mfma_f32_16x16x32_bf16(ax, bIh[5], z4, 0, 0, 0); \
        f32x4 hn = __builtin_amdgcn_mfma_f32_16x16x32_bf16(ah, bHh[5], z4, 0, 0, 0); \
        _Pragma("unroll") for (int r = 0; r < 4; ++r) {                       \
            const float rg = sig2(xr[r] + hr[r] + brz1);                      \
            const float zg = sig2(xz[r] + hz[r] + brz3);                      \
            const float ag = xn[r] + bnx1 + rg * (hn[r] + bnh1);              \
            const float ng = 2.f * sig2(ag) - 1.f;                            \
            hc1[r] = ng + zg * (hc1[r] - ng);                                 \
        }                                                                     \
        if (m < 8) {                                                          \
            _Pragma("unroll") for (int r = 0; r < 4; ++r)                     \
                hw[wr1 + r * 32] = (__bf16)hc1[r];                            \
        }                                                                     \
    }                                                                         \
} while (0)

__global__ __launch_bounds__(256, 4) void gru_kernel(
    const float* __restrict__ x, const float* __restrict__ W_ih,
    const float* __restrict__ W_hh, const float* __restrict__ b_ih,
    const float* __restrict__ b_hh, const float* __restrict__ fc1_w,
    const float* __restrict__ fc1_b, const float* __restrict__ fc2_w,
    const float* __restrict__ fc2_b, float* __restrict__ out)
{
    __shared__ __attribute__((aligned(16))) __bf16 xwin[2 * BUFS];  // 33280 B
    __shared__ __attribute__((aligned(16))) __bf16 hbuf[2048];      // 4 waves x [16][32]
    __shared__ float wbuf[236];  // fc1_w[0..191] fc1_b[192..199] fc2_w[200..231] fc2_b[232..235]

    const int tid = threadIdx.x;
    const int lane = tid & 63;
    const int wid = tid >> 6;          // 0..3
    const int m = lane & 15;
    const int kg = lane >> 4;
    const int w16 = wid << 4;
    const int b0 = blockIdx.x << 6;    // 64 batch rows per block

    // ---- fc weights + zero h ----
    if (tid < 236) {
        float v;
        if (tid < 192) v = fc1_w[tid];
        else if (tid < 200) v = fc1_b[tid - 192];
        else if (tid < 232) v = fc2_w[tid - 200];
        else v = fc2_b[tid - 232];
        wbuf[tid] = v;
    }
    for (int i = tid; i < 2048; i += 256) hbuf[i] = (__bf16)0.f;

    // ---- B fragments + biases from global (L2-hot), pre-scaled by log2e ----
    bf16x8 bIh[6], bHh[6];
    float bx[6], bh[6];
    #pragma unroll
    for (int Tn = 0; Tn < 6; ++Tn) {
        const float sc = (Tn < 4) ? LOG2E : (2.f * LOG2E);
        const int np = Tn * 16 + m;
        const int gp = np >> 5;
        const int jh = np & 31;
        const bool vc = jh < 24;
        const int g = gp * 24 + jh;
        #pragma unroll
        for (int e = 0; e < 8; ++e) {
            const int k = kg * 8 + e;
            bIh[Tn][e] = (__bf16)((vc && k < 26) ? W_ih[g * 26 + k] * sc : 0.f);
            bHh[Tn][e] = (__bf16)((vc && k < 24) ? W_hh[g * 24 + k] * sc : 0.f);
        }
        bx[Tn] = vc ? b_ih[g] * sc : 0.f;
        bh[Tn] = vc ? b_hh[g] * sc : 0.f;
    }
    const float brz0 = bx[0] + bh[0], brz1 = bx[1] + bh[1];
    const float brz2 = bx[2] + bh[2], brz3 = bx[3] + bh[3];
    const float bnx0 = bx[4], bnh0 = bh[4], bnx1 = bx[5], bnh1 = bh[5];

    // ---- staging identity: thread -> (row rr, window slot twn) ----
    const int rr = tid >> 2, twn = tid & 3;
    const float* xrow = x + (size_t)(b0 + rr) * XPITCH;
    f32x2 sb[13];

    // prologue: window 0 (t = 0..3)
    {
        const float* sp = xrow + twn * NIN;
        #pragma unroll
        for (int q = 0; q < 13; ++q) sb[q] = *(const f32x2*)(sp + 2 * q);
        WSTORE(0);
    }
    __syncthreads();

    const int xoff = kg * KGS + (w16 + m) * 8;
    const int ra  = m * 32 + ((kg ^ (m >> 2)) << 3);
    const int wr0 = (kg * 4) * 32 + ((((m >> 3) ^ kg) & 3) << 3) + (m & 7);
    const int wr1 = (kg * 4) * 32 + (((2 ^ kg) & 3) << 3) + m;
    __bf16* hw = &hbuf[wid * 512];

    f32x4 hc0 = {0.f, 0.f, 0.f, 0.f}, hc1 = {0.f, 0.f, 0.f, 0.f};
    const f32x4 z4 = {0.f, 0.f, 0.f, 0.f};

    #pragma unroll 1
    for (int w = 0; w < 7; ++w) {
        // issue next-window loads (consumed by WSTORE two steps later)
        {
            const int tl0 = 4 * (w + 1) + twn;
            const int tl = (tl0 > 29) ? 29 : tl0;   // clamp: window 7 has only t=28,29
            const float* sp = xrow + tl * NIN;
            #pragma unroll
            for (int q = 0; q < 13; ++q) sb[q] = *(const f32x2*)(sp + 2 * q);
        }
        const int bs = w & 1;
        STEP(0, bs);
        STEP(1, bs);
        WSTORE(bs ^ 1);
        STEP(2, bs);
        STEP(3, bs);
        __syncthreads();
    }
    STEP(0, 1);   // t = 28
    STEP(1, 1);   // t = 29

    // ---- epilogue: fc1 -> relu -> fc2 -> softmax, one lane per batch row ----
    if (lane < 16) {
        const int row = lane;
        float hv[24];
        #pragma unroll
        for (int j = 0; j < 24; ++j)
            hv[j] = (float)hw[row * 32 + ((((j >> 3) ^ (row >> 2)) & 3) << 3) + (j & 7)];
        float lg[4] = {wbuf[232], wbuf[233], wbuf[234], wbuf[235]};
        #pragma unroll
        for (int o = 0; o < 8; ++o) {
            float s = wbuf[192 + o];
            #pragma unroll
            for (int j = 0; j < 24; ++j) s += wbuf[o * 24 + j] * hv[j];
            s = fmaxf(s, 0.f);
            #pragma unroll
            for (int c = 0; c < 4; ++c) lg[c] += wbuf[200 + c * 8 + o] * s;
        }
        const float mx = fmaxf(fmaxf(lg[0], lg[1]), fmaxf(lg[2], lg[3]));
        const float e0 = __expf(lg[0] - mx), e1 = __expf(lg[1] - mx);
        const float e2 = __expf(lg[2] - mx), e3 = __expf(lg[3] - mx);
        const float inv = __builtin_amdgcn_rcpf(e0 + e1 + e2 + e3);
        f32x4 pr = {e0 * inv, e1 * inv, e2 * inv, e3 * inv};
        *(f32x4*)&out[(size_t)(b0 + w16 + row) * 4] = pr;
    }
}

extern "C" void kernel_launch(void* const* d_in, const int* in_sizes, int n_in,
                              void* d_out, int out_size, void* d_ws, size_t ws_size,
                              hipStream_t stream) {
    const float* xx    = (const float*)d_in[0];
    const float* w_ih  = (const float*)d_in[1];
    const float* w_hh  = (const float*)d_in[2];
    const float* bih   = (const float*)d_in[3];
    const float* bhh   = (const float*)d_in[4];
    const float* f1w   = (const float*)d_in[5];
    const float* f1b   = (const float*)d_in[6];
    const float* f2w   = (const float*)d_in[7];
    const float* f2b   = (const float*)d_in[8];
    float* outp = (float*)d_out;

    dim3 grid(65536 / 64), block(256);
    gru_kernel<<<grid, block, 0, stream>>>(xx, w_ih, w_hh, bih, bhh, f1w, f1b, f2w, f2b, outp);
}